// Round 1
// baseline (521.038 us; speedup 1.0000x reference)
//
#include <hip/hip_runtime.h>

// Problem constants
#define N_NODES 8192
#define N_EDGES 65536

// ---------- bf16 helpers (OCP bf16 = top 16 bits of f32, RNE) ----------
static __device__ __forceinline__ float bfl(unsigned v){ unsigned u=v<<16; float f; __builtin_memcpy(&f,&u,4); return f; }
static __device__ __forceinline__ float bfh(unsigned v){ unsigned u=v&0xffff0000u; float f; __builtin_memcpy(&f,&u,4); return f; }
static __device__ __forceinline__ float bfs(unsigned short h){ unsigned u=((unsigned)h)<<16; float f; __builtin_memcpy(&f,&u,4); return f; }
static __device__ __forceinline__ unsigned short f2bf(float f){ unsigned u; __builtin_memcpy(&u,&f,4); u += 0x7fffu + ((u>>16)&1u); return (unsigned short)(u>>16); }
static __device__ __forceinline__ unsigned pk(float a, float b){ return (unsigned)f2bf(a) | ((unsigned)f2bf(b)<<16); }
static __device__ __forceinline__ float silu_f(float v){ return v/(1.f+__expf(-v)); }

// ---------- K1: x = node_feats @ W_up / 8  -> ws.x [N,64] f32 ----------
__global__ __launch_bounds__(256) void k_linup(const float* __restrict__ nf,
                                               const float* __restrict__ wup,
                                               float* __restrict__ x){
    __shared__ float s[4][64];
    const int t=threadIdx.x, wv=t>>6, lane=t&63;
    const int n=blockIdx.x*4+wv;
    s[wv][lane]=nf[(size_t)n*64+lane];
    __syncthreads();
    float acc=0.f;
    for(int c=0;c<64;++c) acc += s[wv][c]*wup[c*64+lane];
    x[(size_t)n*64+lane]=acc*0.125f;
}

// ---------- prep: W_big2[i][j][s] bf16: s<4 -> W_r3[i][s*64+j]/8 ; s>=4 -> (W_r3@W_trans)[i][(s-4)*64+j]/128
__global__ __launch_bounds__(256) void k_wbig(const float* __restrict__ wr3,
                                              const float* __restrict__ wtr,
                                              unsigned short* __restrict__ wbig){
    const int i=blockIdx.x, t=threadIdx.x, j=t&63, sl=t>>6;
    wbig[((size_t)i*64+j)*8+sl]=f2bf(wr3[i*256+sl*64+j]*0.125f);
    float acc=0.f;
    for(int k=0;k<256;++k) acc += wr3[i*256+k]*wtr[k*256+sl*64+j];
    wbig[((size_t)i*64+j)*8+4+sl]=f2bf(acc*(1.f/128.f));
}

// ---------- prep: WW2[ten][l][c][w][v] bf16 = sum_u Wlin[l,c,u]*Wskip[l,u,v,w] * (1/256 or 1/4096)
__global__ __launch_bounds__(256) void k_ww(const float* __restrict__ wlin,
                                            const float* __restrict__ wmlin,
                                            const float* __restrict__ wskip,
                                            const float* __restrict__ wmskip,
                                            unsigned short* __restrict__ ww){
    const int b=blockIdx.x, ten=b>>8, lc=b&255, l=lc>>6, c=lc&63;
    const float* WL = ten? wmlin:wlin;
    const float* WS = ten? wmskip:wskip;
    const float scale = ten? (1.f/4096.f):(1.f/256.f);
    const int t=threadIdx.x, w=t&63, vg=t>>6;
    float acc[4]={0.f,0.f,0.f,0.f};
    for(int u=0;u<64;++u){
        float wl=WL[(l*64+c)*64+u];
        #pragma unroll
        for(int q=0;q<4;++q) acc[q]+=wl*WS[((l*64+u)*16+vg*4+q)*64+w];
    }
    unsigned short* op=ww+(size_t)ten*262144+(((l*64+c)*64+w)*16+vg*4);
    uint2 p; p.x=pk(acc[0]*scale,acc[1]*scale); p.y=pk(acc[2]*scale,acc[3]*scale);
    *(uint2*)op=p;
}

// ---------- CSR build ----------
__global__ __launch_bounds__(256) void k_count(const int* __restrict__ recv, int* __restrict__ cnt){
    int e=blockIdx.x*256+threadIdx.x;
    atomicAdd(&cnt[recv[e]],1);
}
__global__ __launch_bounds__(1024) void k_scan(const int* __restrict__ cnt, int* __restrict__ rowptr, int* __restrict__ cur){
    __shared__ int s[1024];
    const int t=threadIdx.x;
    int c[8]; int sum=0;
    #pragma unroll
    for(int i=0;i<8;++i){ c[i]=cnt[t*8+i]; sum+=c[i]; }
    s[t]=sum; __syncthreads();
    for(int off=1;off<1024;off<<=1){
        int v=s[t]; int add=(t>=off)? s[t-off]:0;
        __syncthreads();
        s[t]=v+add;
        __syncthreads();
    }
    int run=s[t]-sum;
    #pragma unroll
    for(int i=0;i<8;++i){ rowptr[t*8+i]=run; cur[t*8+i]=run; run+=c[i]; }
    if(t==1023) rowptr[8192]=run;
}
__global__ __launch_bounds__(256) void k_scatter(const int* __restrict__ recv, int* __restrict__ cur, int* __restrict__ elist){
    int e=blockIdx.x*256+threadIdx.x;
    int r=recv[e];
    int p=atomicAdd(&cur[r],1);
    elist[p]=e;
}

// ---------- K2: per-edge radial MLP + weight apply. Writes wxc[e][c][8] bf16 (wx l0..3, wxm l0..3), man[e][16], ed[e]
__global__ __launch_bounds__(256) void k_edge(
    const float* __restrict__ ef, const float* __restrict__ mminv,
    const float* __restrict__ mattr, const int* __restrict__ sender,
    const float* __restrict__ wr0, const float* __restrict__ wr1,
    const float* __restrict__ wr2, const float* __restrict__ wdens,
    const unsigned short* __restrict__ wbig, const float* __restrict__ x,
    unsigned short* __restrict__ wxc, float* __restrict__ man, float* __restrict__ ed)
{
    __shared__ unsigned short w0s[1024];
    __shared__ unsigned short w1s[4096];
    __shared__ unsigned short w2s[4096];
    __shared__ float hA[64][64];
    __shared__ float hB[64][64];
    __shared__ int sbuf[64];
    const int t=threadIdx.x;
    const int tile=blockIdx.x*64;
    // stage MLP weights (scales folded)
    for(int q=t;q<1024;q+=256) w0s[q]=f2bf(wr0[q]*0.25f);
    for(int q=t;q<4096;q+=256){ w1s[q]=f2bf(wr1[q]*0.125f); w2s[q]=f2bf(wr2[q]*0.125f); }
    const int wv=t>>6, el=t&63, e=tile+el;
    if(wv==0){
        sbuf[el]=sender[e];
    } else if(wv==1){
        float acc=0.f;
        #pragma unroll
        for(int r=0;r<8;++r){ float v=ef[(size_t)e*8+r]; hA[el][r]=v; acc+=v*wdens[r]; }
        acc*=0.35355339059327373f;           // 1/sqrt(8)
        float q2=acc*acc;
        float ex=__expf(2.f*q2);
        ed[e]=1.f-2.f/(ex+1.f);             // tanh(q2), q2>=0
    } else if(wv==2){
        int s=sender[e];
        #pragma unroll
        for(int r=0;r<8;++r) hA[el][8+r]=mminv[(size_t)s*8+r];
    } else {
        int s=sender[e];
        #pragma unroll
        for(int m=0;m<16;++m) man[(size_t)e*16+m]=mattr[(size_t)s*16+m];
    }
    __syncthreads();
    const int j=el, eg=wv;
    // layer1 (16->64): hA[:, :16] -> hB
    for(int k4=0;k4<4;++k4){
        int e0=eg*16+k4*4;
        float a0=0,a1=0,a2=0,a3=0;
        for(int i=0;i<16;++i){
            float w=bfs(w0s[i*64+j]);
            a0+=hA[e0+0][i]*w; a1+=hA[e0+1][i]*w; a2+=hA[e0+2][i]*w; a3+=hA[e0+3][i]*w;
        }
        hB[e0+0][j]=silu_f(a0); hB[e0+1][j]=silu_f(a1); hB[e0+2][j]=silu_f(a2); hB[e0+3][j]=silu_f(a3);
    }
    __syncthreads();
    // layer2 (64->64): hB -> hA
    for(int k4=0;k4<4;++k4){
        int e0=eg*16+k4*4;
        float a0=0,a1=0,a2=0,a3=0;
        for(int i=0;i<64;++i){
            float w=bfs(w1s[i*64+j]);
            a0+=hB[e0+0][i]*w; a1+=hB[e0+1][i]*w; a2+=hB[e0+2][i]*w; a3+=hB[e0+3][i]*w;
        }
        hA[e0+0][j]=silu_f(a0); hA[e0+1][j]=silu_f(a1); hA[e0+2][j]=silu_f(a2); hA[e0+3][j]=silu_f(a3);
    }
    __syncthreads();
    // layer3 (64->64): hA -> hB
    for(int k4=0;k4<4;++k4){
        int e0=eg*16+k4*4;
        float a0=0,a1=0,a2=0,a3=0;
        for(int i=0;i<64;++i){
            float w=bfs(w2s[i*64+j]);
            a0+=hA[e0+0][i]*w; a1+=hA[e0+1][i]*w; a2+=hA[e0+2][i]*w; a3+=hA[e0+3][i]*w;
        }
        hB[e0+0][j]=silu_f(a0); hB[e0+1][j]=silu_f(a1); hB[e0+2][j]=silu_f(a2); hB[e0+3][j]=silu_f(a3);
    }
    __syncthreads();
    // phase B: tp_w/tp_wm = h3 @ W_big2, fold xj, write bf16
    float accw[16][4]; float accm[16][4];
    #pragma unroll
    for(int eo=0;eo<16;++eo){
        #pragma unroll
        for(int l=0;l<4;++l){ accw[eo][l]=0.f; accm[eo][l]=0.f; }
    }
    const int e0=eg*16;
    for(int i=0;i<64;++i){
        uint4 r=*(const uint4*)(wbig+((size_t)i*64+j)*8);
        float w0=bfl(r.x),w1=bfh(r.x),w2=bfl(r.y),w3=bfh(r.y);
        float m0=bfl(r.z),m1=bfh(r.z),m2=bfl(r.w),m3=bfh(r.w);
        #pragma unroll
        for(int eo=0;eo<16;++eo){
            float h=hB[e0+eo][i];
            accw[eo][0]+=h*w0; accw[eo][1]+=h*w1; accw[eo][2]+=h*w2; accw[eo][3]+=h*w3;
            accm[eo][0]+=h*m0; accm[eo][1]+=h*m1; accm[eo][2]+=h*m2; accm[eo][3]+=h*m3;
        }
    }
    #pragma unroll
    for(int eo=0;eo<16;++eo){
        int elc=e0+eo;
        int s=sbuf[elc];
        float xj=x[(size_t)s*64+j];
        uint4 o;
        o.x=pk(accw[eo][0]*xj, accw[eo][1]*xj);
        o.y=pk(accw[eo][2]*xj, accw[eo][3]*xj);
        o.z=pk(accm[eo][0]*xj, accm[eo][1]*xj);
        o.w=pk(accm[eo][2]*xj, accm[eo][3]*xj);
        *(uint4*)(wxc+((size_t)(tile+elc)*64+j)*8)=o;
    }
}

// ---------- K3: wave-per-node gather; writes msgd (msg/(1+D)) and mm_raw into d_out
__global__ __launch_bounds__(256) void k_gather(
    const int* __restrict__ rowptr, const int* __restrict__ elist,
    const unsigned short* __restrict__ wxc, const float* __restrict__ ea,
    const float* __restrict__ man, const float* __restrict__ ed,
    float* __restrict__ out)
{
    const int t=threadIdx.x, wv=t>>6, lane=t&63;
    const int n=blockIdx.x*4+wv;
    const int r0=rowptr[n], r1=rowptr[n+1];
    float msg[16]; float mm[16];
    #pragma unroll
    for(int m=0;m<16;++m){ msg[m]=0.f; mm[m]=0.f; }
    float dens=0.f;
    for(int k=r0;k<r1;++k){
        int e=elist[k];
        uint4 r=*(const uint4*)(wxc+((size_t)e*64+lane)*8);
        float wx0=bfl(r.x),wx1=bfh(r.x),wx2=bfl(r.y),wx3=bfh(r.y);
        float wm0=bfl(r.z),wm1=bfh(r.z),wm2=bfl(r.w),wm3=bfh(r.w);
        dens+=ed[e];
        const float4* eap=(const float4*)(ea+(size_t)e*16);
        const float4* map=(const float4*)(man+(size_t)e*16);
        float4 A0=eap[0],A1=eap[1],A2=eap[2],A3=eap[3];
        float4 B0=map[0],B1=map[1],B2=map[2],B3=map[3];
        msg[0]+=wx0*A0.x;
        msg[1]+=wx1*A0.y;  msg[2]+=wx1*A0.z;  msg[3]+=wx1*A0.w;
        msg[4]+=wx2*A1.x;  msg[5]+=wx2*A1.y;  msg[6]+=wx2*A1.z;  msg[7]+=wx2*A1.w;  msg[8]+=wx2*A2.x;
        msg[9]+=wx3*A2.y;  msg[10]+=wx3*A2.z; msg[11]+=wx3*A2.w;
        msg[12]+=wx3*A3.x; msg[13]+=wx3*A3.y; msg[14]+=wx3*A3.z; msg[15]+=wx3*A3.w;
        mm[0]+=wm0*B0.x;
        mm[1]+=wm1*B0.y;  mm[2]+=wm1*B0.z;  mm[3]+=wm1*B0.w;
        mm[4]+=wm2*B1.x;  mm[5]+=wm2*B1.y;  mm[6]+=wm2*B1.z;  mm[7]+=wm2*B1.w;  mm[8]+=wm2*B2.x;
        mm[9]+=wm3*B2.y;  mm[10]+=wm3*B2.z; mm[11]+=wm3*B2.w;
        mm[12]+=wm3*B3.x; mm[13]+=wm3*B3.y; mm[14]+=wm3*B3.z; mm[15]+=wm3*B3.w;
    }
    float inv=1.f/(1.f+dens);
    float* mp=out+(size_t)n*1024+lane*16;
    ((float4*)mp)[0]=make_float4(msg[0]*inv,msg[1]*inv,msg[2]*inv,msg[3]*inv);
    ((float4*)mp)[1]=make_float4(msg[4]*inv,msg[5]*inv,msg[6]*inv,msg[7]*inv);
    ((float4*)mp)[2]=make_float4(msg[8]*inv,msg[9]*inv,msg[10]*inv,msg[11]*inv);
    ((float4*)mp)[3]=make_float4(msg[12]*inv,msg[13]*inv,msg[14]*inv,msg[15]*inv);
    float* qp=out+8388608+(size_t)n*1024+lane*16;
    ((float4*)qp)[0]=make_float4(mm[0],mm[1],mm[2],mm[3]);
    ((float4*)qp)[1]=make_float4(mm[4],mm[5],mm[6],mm[7]);
    ((float4*)qp)[2]=make_float4(mm[8],mm[9],mm[10],mm[11]);
    ((float4*)qp)[3]=make_float4(mm[12],mm[13],mm[14],mm[15]);
}

// ---------- K4: fused per_l_linear + skip_tp: out[n,w,m] = sum_c msgd[n,c,m] * (sum_v attrs[n,v]*WW[l,c,v,w])
// In-place on d_out per 16-node block (staged to LDS first).
__global__ __launch_bounds__(256) void k_final(const float* __restrict__ attrs,
                                               const unsigned short* __restrict__ ww,
                                               float* __restrict__ out){
    const int blk=blockIdx.x, ten=blk>>9, nb=(blk&511)*16;
    float* base=out+(size_t)ten*8388608;
    const unsigned short* wwt=ww+(size_t)ten*262144;
    __shared__ unsigned short sm[16384];   // [16 nodes][64 c][16 m] bf16
    __shared__ float sat[256];             // [16 nodes][16 v]
    const int t=threadIdx.x;
    const float* src=base+(size_t)nb*1024;
    for(int q=t;q<4096;q+=256){
        float4 v=((const float4*)src)[q];
        uint2 p; p.x=pk(v.x,v.y); p.y=pk(v.z,v.w);
        ((uint2*)sm)[q]=p;
    }
    sat[t]=attrs[(size_t)(nb+(t>>4))*16+(t&15)];
    __syncthreads();
    const int w=t&63, bs=t>>6;
    float a[4][16];
    #pragma unroll
    for(int b=0;b<4;++b){
        #pragma unroll
        for(int v=0;v<16;++v) a[b][v]=sat[(bs*4+b)*16+v];
    }
    float acc[4][16];
    #pragma unroll
    for(int b=0;b<4;++b){
        #pragma unroll
        for(int m=0;m<16;++m) acc[b][m]=0.f;
    }
    constexpr int M0[4]={0,1,4,9};
    constexpr int DL[4]={1,3,5,7};
    #pragma unroll
    for(int l=0;l<4;++l){
        for(int c=0;c<64;++c){
            const unsigned short* wp=wwt+(((l*64+c)*64+w)<<4);
            uint4 q0=*(const uint4*)wp;
            uint4 q1=*(const uint4*)(wp+8);
            float w00=bfl(q0.x),w01=bfh(q0.x),w02=bfl(q0.y),w03=bfh(q0.y);
            float w04=bfl(q0.z),w05=bfh(q0.z),w06=bfl(q0.w),w07=bfh(q0.w);
            float w08=bfl(q1.x),w09=bfh(q1.x),w10=bfl(q1.y),w11=bfh(q1.y);
            float w12=bfl(q1.z),w13=bfh(q1.z),w14=bfl(q1.w),w15=bfh(q1.w);
            #pragma unroll
            for(int b=0;b<4;++b){
                float Wn = a[b][0]*w00+a[b][1]*w01+a[b][2]*w02+a[b][3]*w03
                         + a[b][4]*w04+a[b][5]*w05+a[b][6]*w06+a[b][7]*w07
                         + a[b][8]*w08+a[b][9]*w09+a[b][10]*w10+a[b][11]*w11
                         + a[b][12]*w12+a[b][13]*w13+a[b][14]*w14+a[b][15]*w15;
                #pragma unroll
                for(int mi=0;mi<DL[l];++mi){
                    int m=M0[l]+mi;
                    float mv=bfs(sm[((bs*4+b)*64+c)*16+m]);
                    acc[b][m]+=mv*Wn;
                }
            }
        }
    }
    #pragma unroll
    for(int b=0;b<4;++b){
        float* op=base+(size_t)(nb+bs*4+b)*1024+w*16;
        ((float4*)op)[0]=make_float4(acc[b][0],acc[b][1],acc[b][2],acc[b][3]);
        ((float4*)op)[1]=make_float4(acc[b][4],acc[b][5],acc[b][6],acc[b][7]);
        ((float4*)op)[2]=make_float4(acc[b][8],acc[b][9],acc[b][10],acc[b][11]);
        ((float4*)op)[3]=make_float4(acc[b][12],acc[b][13],acc[b][14],acc[b][15]);
    }
}

extern "C" void kernel_launch(void* const* d_in, const int* in_sizes, int n_in,
                              void* d_out, int out_size, void* d_ws, size_t ws_size,
                              hipStream_t stream) {
    const float* node_attrs=(const float*)d_in[0];
    const float* node_feats=(const float*)d_in[1];
    const float* edge_attrs=(const float*)d_in[2];
    const float* edge_feats=(const float*)d_in[3];
    const int*   eidx_in  =(const int*)  d_in[4];
    const int*   sender   =eidx_in;
    const int*   recv     =eidx_in+N_EDGES;
    const float* mminv    =(const float*)d_in[5];
    const float* mattr    =(const float*)d_in[6];
    const float* wup      =(const float*)d_in[7];
    const float* wr0      =(const float*)d_in[8];
    const float* wr1      =(const float*)d_in[9];
    const float* wr2      =(const float*)d_in[10];
    const float* wr3      =(const float*)d_in[11];
    const float* wtr      =(const float*)d_in[12];
    const float* wdens    =(const float*)d_in[13];
    const float* wlin     =(const float*)d_in[14];
    const float* wmlin    =(const float*)d_in[15];
    const float* wskip    =(const float*)d_in[16];
    const float* wmskip   =(const float*)d_in[17];

    char* ws=(char*)d_ws;
    float*          x     =(float*)(ws+0);                      //  2 MB
    unsigned short* wxc   =(unsigned short*)(ws+2097152);       // 64 MB
    float*          man   =(float*)(ws+69206016);               //  4 MB
    float*          ed    =(float*)(ws+73400320);               // 256 KB
    unsigned short* wbig  =(unsigned short*)(ws+73662464);      // 64 KB
    unsigned short* wwp   =(unsigned short*)(ws+73728000);      //  1 MB
    int*            cnt   =(int*)(ws+74776576);                 // 32 KB
    int*            rowptr=(int*)(ws+74809344);                 // 32 KB + 4
    int*            cur   =(int*)(ws+74842368);                 // 32 KB
    int*            elist =(int*)(ws+74875136);                 // 256 KB
    if(ws_size < (size_t)75137280) return;   // insufficient scratch: bail (will fail check loudly)

    float* out=(float*)d_out;

    hipMemsetAsync(cnt,0,32768,stream);
    k_linup  <<<dim3(2048),dim3(256),0,stream>>>(node_feats,wup,x);
    k_wbig   <<<dim3(64),  dim3(256),0,stream>>>(wr3,wtr,wbig);
    k_ww     <<<dim3(512), dim3(256),0,stream>>>(wlin,wmlin,wskip,wmskip,wwp);
    k_count  <<<dim3(256), dim3(256),0,stream>>>(recv,cnt);
    k_scan   <<<dim3(1),   dim3(1024),0,stream>>>(cnt,rowptr,cur);
    k_scatter<<<dim3(256), dim3(256),0,stream>>>(recv,cur,elist);
    k_edge   <<<dim3(1024),dim3(256),0,stream>>>(edge_feats,mminv,mattr,sender,
                                                 wr0,wr1,wr2,wdens,wbig,x,wxc,man,ed);
    k_gather <<<dim3(2048),dim3(256),0,stream>>>(rowptr,elist,wxc,edge_attrs,man,ed,out);
    k_final  <<<dim3(1024),dim3(256),0,stream>>>(node_attrs,wwp,out);
}

// Round 2
// 361.830 us; speedup vs baseline: 1.4400x; 1.4400x over previous
//
#include <hip/hip_runtime.h>

// Problem constants
#define N_NODES 8192
#define N_EDGES 65536

typedef __attribute__((ext_vector_type(8))) short bf16x8;
typedef __attribute__((ext_vector_type(4))) float f32x4;

// ---------- bf16 helpers (OCP bf16 = top 16 bits of f32, RNE) ----------
static __device__ __forceinline__ float bfl(unsigned v){ unsigned u=v<<16; float f; __builtin_memcpy(&f,&u,4); return f; }
static __device__ __forceinline__ float bfh(unsigned v){ unsigned u=v&0xffff0000u; float f; __builtin_memcpy(&f,&u,4); return f; }
static __device__ __forceinline__ float bfs(unsigned short h){ unsigned u=((unsigned)h)<<16; float f; __builtin_memcpy(&f,&u,4); return f; }
static __device__ __forceinline__ unsigned short f2bf(float f){ unsigned u; __builtin_memcpy(&u,&f,4); u += 0x7fffu + ((u>>16)&1u); return (unsigned short)(u>>16); }
static __device__ __forceinline__ unsigned pk(float a, float b){ return (unsigned)f2bf(a) | ((unsigned)f2bf(b)<<16); }
static __device__ __forceinline__ float silu_f(float v){ return v/(1.f+__expf(-v)); }

// ---------- K1: x = node_feats @ W_up / 8  -> ws.x [N,64] f32 ----------
__global__ __launch_bounds__(256) void k_linup(const float* __restrict__ nf,
                                               const float* __restrict__ wup,
                                               float* __restrict__ x){
    __shared__ float s[4][64];
    const int t=threadIdx.x, wv=t>>6, lane=t&63;
    const int n=blockIdx.x*4+wv;
    s[wv][lane]=nf[(size_t)n*64+lane];
    __syncthreads();
    float acc=0.f;
    for(int c=0;c<64;++c) acc += s[wv][c]*wup[c*64+lane];
    x[(size_t)n*64+lane]=acc*0.125f;
}

// ---------- prep: W_big2[i][j][s] bf16: s<4 -> W_r3[i][s*64+j]/8 ; s>=4 -> (W_r3@W_trans)[i][(s-4)*64+j]/128
__global__ __launch_bounds__(256) void k_wbig(const float* __restrict__ wr3,
                                              const float* __restrict__ wtr,
                                              unsigned short* __restrict__ wbig){
    const int i=blockIdx.x, t=threadIdx.x, j=t&63, sl=t>>6;
    wbig[((size_t)i*64+j)*8+sl]=f2bf(wr3[i*256+sl*64+j]*0.125f);
    float acc=0.f;
    for(int k=0;k<256;++k) acc += wr3[i*256+k]*wtr[k*256+sl*64+j];
    wbig[((size_t)i*64+j)*8+4+sl]=f2bf(acc*(1.f/128.f));
}

// ---------- prep: MFMA B-fragment table for the fused node contraction.
// WW[l,c,v,w] = sum_u Wlin[l,c,u]*Wskip[l,u,v,w] * (1/256 or 1/4096)
// Fragment (ten,l,c,wg): lane(0..31) holds 8 bf16 = WW[l,c, v=(lane>>4)*8+e, w=wg*16+(lane&15)]
__global__ __launch_bounds__(256) void k_wwf(const float* __restrict__ wlin,
                                             const float* __restrict__ wmlin,
                                             const float* __restrict__ wskip,
                                             const float* __restrict__ wmskip,
                                             unsigned* __restrict__ wwf){
    const int b=blockIdx.x, ten=b>>8, lc=b&255, l=lc>>6, c=lc&63;
    const float* WL = ten? wmlin:wlin;
    const float* WS = ten? wmskip:wskip;
    const float scale = ten? (1.f/4096.f):(1.f/256.f);
    const int t=threadIdx.x, wg=t>>6, s=t&63, lane=s>>1, half=s&1;
    const int kg=lane>>4, w=wg*16+(lane&15);
    const int v0=kg*8+half*4;
    float a0=0,a1=0,a2=0,a3=0;
    for(int u=0;u<64;++u){
        float wl=WL[(l*64+c)*64+u];
        const float* wsp=&WS[(((l*64+u)*16+v0)*64)+w];
        a0+=wl*wsp[0]; a1+=wl*wsp[64]; a2+=wl*wsp[128]; a3+=wl*wsp[192];
    }
    size_t fi=(((size_t)ten*4+l)*64+c)*4+wg;
    unsigned* op=wwf + (fi*32+lane)*4 + half*2;
    op[0]=pk(a0*scale,a1*scale); op[1]=pk(a2*scale,a3*scale);
}

// ---------- CSR build ----------
__global__ __launch_bounds__(256) void k_count(const int* __restrict__ recv, int* __restrict__ cnt){
    int e=blockIdx.x*256+threadIdx.x;
    atomicAdd(&cnt[recv[e]],1);
}
__global__ __launch_bounds__(1024) void k_scan(const int* __restrict__ cnt, int* __restrict__ rowptr, int* __restrict__ cur){
    __shared__ int s[1024];
    const int t=threadIdx.x;
    int c[8]; int sum=0;
    #pragma unroll
    for(int i=0;i<8;++i){ c[i]=cnt[t*8+i]; sum+=c[i]; }
    s[t]=sum; __syncthreads();
    for(int off=1;off<1024;off<<=1){
        int v=s[t]; int add=(t>=off)? s[t-off]:0;
        __syncthreads();
        s[t]=v+add;
        __syncthreads();
    }
    int run=s[t]-sum;
    #pragma unroll
    for(int i=0;i<8;++i){ rowptr[t*8+i]=run; cur[t*8+i]=run; run+=c[i]; }
    if(t==1023) rowptr[8192]=run;
}
__global__ __launch_bounds__(256) void k_scatter(const int* __restrict__ recv, int* __restrict__ cur, int* __restrict__ elist){
    int e=blockIdx.x*256+threadIdx.x;
    int r=recv[e];
    int p=atomicAdd(&cur[r],1);
    elist[p]=e;
}

// ---------- K2: per-edge radial MLP + weight apply. Writes wxc[e][c][8] bf16 (wx l0..3, wxm l0..3), man[e][16], ed[e]
__global__ __launch_bounds__(256) void k_edge(
    const float* __restrict__ ef, const float* __restrict__ mminv,
    const float* __restrict__ mattr, const int* __restrict__ sender,
    const float* __restrict__ wr0, const float* __restrict__ wr1,
    const float* __restrict__ wr2, const float* __restrict__ wdens,
    const unsigned short* __restrict__ wbig, const float* __restrict__ x,
    unsigned short* __restrict__ wxc, float* __restrict__ man, float* __restrict__ ed)
{
    __shared__ unsigned short w0s[1024];
    __shared__ unsigned short w1s[4096];
    __shared__ unsigned short w2s[4096];
    __shared__ float hA[64][64];
    __shared__ float hB[64][64];
    __shared__ int sbuf[64];
    const int t=threadIdx.x;
    const int tile=blockIdx.x*64;
    for(int q=t;q<1024;q+=256) w0s[q]=f2bf(wr0[q]*0.25f);
    for(int q=t;q<4096;q+=256){ w1s[q]=f2bf(wr1[q]*0.125f); w2s[q]=f2bf(wr2[q]*0.125f); }
    const int wv=t>>6, el=t&63, e=tile+el;
    if(wv==0){
        sbuf[el]=sender[e];
    } else if(wv==1){
        float acc=0.f;
        #pragma unroll
        for(int r=0;r<8;++r){ float v=ef[(size_t)e*8+r]; hA[el][r]=v; acc+=v*wdens[r]; }
        acc*=0.35355339059327373f;
        float q2=acc*acc;
        float ex=__expf(2.f*q2);
        ed[e]=1.f-2.f/(ex+1.f);
    } else if(wv==2){
        int s=sender[e];
        #pragma unroll
        for(int r=0;r<8;++r) hA[el][8+r]=mminv[(size_t)s*8+r];
    } else {
        int s=sender[e];
        #pragma unroll
        for(int m=0;m<16;++m) man[(size_t)e*16+m]=mattr[(size_t)s*16+m];
    }
    __syncthreads();
    const int j=el, eg=wv;
    for(int k4=0;k4<4;++k4){
        int e0=eg*16+k4*4;
        float a0=0,a1=0,a2=0,a3=0;
        for(int i=0;i<16;++i){
            float w=bfs(w0s[i*64+j]);
            a0+=hA[e0+0][i]*w; a1+=hA[e0+1][i]*w; a2+=hA[e0+2][i]*w; a3+=hA[e0+3][i]*w;
        }
        hB[e0+0][j]=silu_f(a0); hB[e0+1][j]=silu_f(a1); hB[e0+2][j]=silu_f(a2); hB[e0+3][j]=silu_f(a3);
    }
    __syncthreads();
    for(int k4=0;k4<4;++k4){
        int e0=eg*16+k4*4;
        float a0=0,a1=0,a2=0,a3=0;
        for(int i=0;i<64;++i){
            float w=bfs(w1s[i*64+j]);
            a0+=hB[e0+0][i]*w; a1+=hB[e0+1][i]*w; a2+=hB[e0+2][i]*w; a3+=hB[e0+3][i]*w;
        }
        hA[e0+0][j]=silu_f(a0); hA[e0+1][j]=silu_f(a1); hA[e0+2][j]=silu_f(a2); hA[e0+3][j]=silu_f(a3);
    }
    __syncthreads();
    for(int k4=0;k4<4;++k4){
        int e0=eg*16+k4*4;
        float a0=0,a1=0,a2=0,a3=0;
        for(int i=0;i<64;++i){
            float w=bfs(w2s[i*64+j]);
            a0+=hA[e0+0][i]*w; a1+=hA[e0+1][i]*w; a2+=hA[e0+2][i]*w; a3+=hA[e0+3][i]*w;
        }
        hB[e0+0][j]=silu_f(a0); hB[e0+1][j]=silu_f(a1); hB[e0+2][j]=silu_f(a2); hB[e0+3][j]=silu_f(a3);
    }
    __syncthreads();
    float accw[16][4]; float accm[16][4];
    #pragma unroll
    for(int eo=0;eo<16;++eo){
        #pragma unroll
        for(int l=0;l<4;++l){ accw[eo][l]=0.f; accm[eo][l]=0.f; }
    }
    const int e0=eg*16;
    for(int i=0;i<64;++i){
        uint4 r=*(const uint4*)(wbig+((size_t)i*64+j)*8);
        float w0=bfl(r.x),w1=bfh(r.x),w2=bfl(r.y),w3=bfh(r.y);
        float m0=bfl(r.z),m1=bfh(r.z),m2=bfl(r.w),m3=bfh(r.w);
        #pragma unroll
        for(int eo=0;eo<16;++eo){
            float h=hB[e0+eo][i];
            accw[eo][0]+=h*w0; accw[eo][1]+=h*w1; accw[eo][2]+=h*w2; accw[eo][3]+=h*w3;
            accm[eo][0]+=h*m0; accm[eo][1]+=h*m1; accm[eo][2]+=h*m2; accm[eo][3]+=h*m3;
        }
    }
    #pragma unroll
    for(int eo=0;eo<16;++eo){
        int elc=e0+eo;
        int s=sbuf[elc];
        float xj=x[(size_t)s*64+j];
        uint4 o;
        o.x=pk(accw[eo][0]*xj, accw[eo][1]*xj);
        o.y=pk(accw[eo][2]*xj, accw[eo][3]*xj);
        o.z=pk(accm[eo][0]*xj, accm[eo][1]*xj);
        o.w=pk(accm[eo][2]*xj, accm[eo][3]*xj);
        *(uint4*)(wxc+((size_t)(tile+elc)*64+j)*8)=o;
    }
}

// ---------- K3: wave-per-node gather; writes msgd (msg/(1+D)) and mm_raw into d_out
__global__ __launch_bounds__(256) void k_gather(
    const int* __restrict__ rowptr, const int* __restrict__ elist,
    const unsigned short* __restrict__ wxc, const float* __restrict__ ea,
    const float* __restrict__ man, const float* __restrict__ ed,
    float* __restrict__ out)
{
    const int t=threadIdx.x, wv=t>>6, lane=t&63;
    const int n=blockIdx.x*4+wv;
    const int r0=rowptr[n], r1=rowptr[n+1];
    float msg[16]; float mm[16];
    #pragma unroll
    for(int m=0;m<16;++m){ msg[m]=0.f; mm[m]=0.f; }
    float dens=0.f;
    for(int k=r0;k<r1;++k){
        int e=elist[k];
        uint4 r=*(const uint4*)(wxc+((size_t)e*64+lane)*8);
        float wx0=bfl(r.x),wx1=bfh(r.x),wx2=bfl(r.y),wx3=bfh(r.y);
        float wm0=bfl(r.z),wm1=bfh(r.z),wm2=bfl(r.w),wm3=bfh(r.w);
        dens+=ed[e];
        const float4* eap=(const float4*)(ea+(size_t)e*16);
        const float4* map=(const float4*)(man+(size_t)e*16);
        float4 A0=eap[0],A1=eap[1],A2=eap[2],A3=eap[3];
        float4 B0=map[0],B1=map[1],B2=map[2],B3=map[3];
        msg[0]+=wx0*A0.x;
        msg[1]+=wx1*A0.y;  msg[2]+=wx1*A0.z;  msg[3]+=wx1*A0.w;
        msg[4]+=wx2*A1.x;  msg[5]+=wx2*A1.y;  msg[6]+=wx2*A1.z;  msg[7]+=wx2*A1.w;  msg[8]+=wx2*A2.x;
        msg[9]+=wx3*A2.y;  msg[10]+=wx3*A2.z; msg[11]+=wx3*A2.w;
        msg[12]+=wx3*A3.x; msg[13]+=wx3*A3.y; msg[14]+=wx3*A3.z; msg[15]+=wx3*A3.w;
        mm[0]+=wm0*B0.x;
        mm[1]+=wm1*B0.y;  mm[2]+=wm1*B0.z;  mm[3]+=wm1*B0.w;
        mm[4]+=wm2*B1.x;  mm[5]+=wm2*B1.y;  mm[6]+=wm2*B1.z;  mm[7]+=wm2*B1.w;  mm[8]+=wm2*B2.x;
        mm[9]+=wm3*B2.y;  mm[10]+=wm3*B2.z; mm[11]+=wm3*B2.w;
        mm[12]+=wm3*B3.x; mm[13]+=wm3*B3.y; mm[14]+=wm3*B3.z; mm[15]+=wm3*B3.w;
    }
    float inv=1.f/(1.f+dens);
    float* mp=out+(size_t)n*1024+lane*16;
    ((float4*)mp)[0]=make_float4(msg[0]*inv,msg[1]*inv,msg[2]*inv,msg[3]*inv);
    ((float4*)mp)[1]=make_float4(msg[4]*inv,msg[5]*inv,msg[6]*inv,msg[7]*inv);
    ((float4*)mp)[2]=make_float4(msg[8]*inv,msg[9]*inv,msg[10]*inv,msg[11]*inv);
    ((float4*)mp)[3]=make_float4(msg[12]*inv,msg[13]*inv,msg[14]*inv,msg[15]*inv);
    float* qp=out+8388608+(size_t)n*1024+lane*16;
    ((float4*)qp)[0]=make_float4(mm[0],mm[1],mm[2],mm[3]);
    ((float4*)qp)[1]=make_float4(mm[4],mm[5],mm[6],mm[7]);
    ((float4*)qp)[2]=make_float4(mm[8],mm[9],mm[10],mm[11]);
    ((float4*)qp)[3]=make_float4(mm[12],mm[13],mm[14],mm[15]);
}

// ---------- K4: fused per_l_linear + skip_tp via MFMA (step A) + VALU (step B).
// Step A (MFMA): Wn[n, c, w] = sum_v attrs_bf16[n,v] * WWf[l,c,v,w]   (K=16 padded to 32)
// Step B (VALU): out[n, w, m] = sum_c msg_bf16[n,c,m] * Wn[n, c, w]   (l = l(m))
// In-place on d_out per 16-node slab (staged to LDS bf16 first).
__global__ __launch_bounds__(256) void k_final2(const float* __restrict__ attrs,
                                                const unsigned* __restrict__ wwf,
                                                float* __restrict__ out){
    __shared__ float WnS[8*16*68];          // [(l*2+cj)*16 + n][68w pad] f32   (34816 B)
    __shared__ unsigned short msgS[16384];  // [c][n][m] bf16                   (32768 B)
    const int blk=blockIdx.x, ten=blk>>9, nb=(blk&511)*16;
    float* base=out+(size_t)ten*8388608;
    const int t=threadIdx.x, lane=t&63, wg=t>>6;

    // phase 0: stage msg slab (f32 [n][c][m]) -> msgS bf16 [c][n][m]
    const float4* src=(const float4*)(base+(size_t)nb*1024);
    #pragma unroll
    for(int j=0;j<16;++j){
        int idx=t+256*j;
        float4 f=src[idx];
        int n=idx>>8, c=(idx>>2)&63, m0=(idx&3)<<2;
        unsigned* dst=(unsigned*)&msgS[(c*16+n)*16+m0];
        dst[0]=pk(f.x,f.y); dst[1]=pk(f.z,f.w);
    }
    // A-fragment: attrs[nb+row][v], row=lane&15, v=(lane>>4)*8+e (zero for lane>=32)
    bf16x8 afrag;
    {
        int nloc=lane&15, kg=lane>>4;
        if(kg<2){
            const float* ap=attrs+(size_t)(nb+nloc)*16+kg*8;
            #pragma unroll
            for(int i=0;i<8;++i) afrag[i]=(short)f2bf(ap[i]);
        } else {
            #pragma unroll
            for(int i=0;i<8;++i) afrag[i]=0;
        }
    }
    const int ni=t>>4, mi=t&15;
    const int lm=(mi==0)?0:(mi<4)?1:(mi<9)?2:3;
    float acc[64];
    #pragma unroll
    for(int w=0;w<64;++w) acc[w]=0.f;

    const uint4* wwf4=(const uint4*)wwf;
    uint4 bcur[8], bnxt[8];
    #pragma unroll
    for(int q=0;q<8;++q){              // q = l*2+cj, chunk 0 -> c=cj
        int l=q>>1, c=q&1;
        size_t fi=(((size_t)ten*4+l)*64+c)*4+wg;
        bcur[q]=(lane<32)? wwf4[fi*32+lane] : make_uint4(0,0,0,0);
    }
    __syncthreads();

    for(int ch=0;ch<32;++ch){
        // step A: 8 MFMAs (this wave's w-group), write Wn f32 to LDS
        const int colw=wg*16+(lane&15);
        const int g4=(lane>>4)*4;
        #pragma unroll
        for(int q=0;q<8;++q){
            bf16x8 b; __builtin_memcpy(&b,&bcur[q],16);
            f32x4 z={0.f,0.f,0.f,0.f};
            f32x4 d=__builtin_amdgcn_mfma_f32_16x16x32_bf16(afrag,b,z,0,0,0);
            float* wp=&WnS[(q*16+g4)*68+colw];
            wp[0]=d[0]; wp[68]=d[1]; wp[136]=d[2]; wp[204]=d[3];
        }
        // prefetch next chunk's B-fragments (hidden under step B)
        if(ch<31){
            #pragma unroll
            for(int q=0;q<8;++q){
                int l=q>>1, c=(ch+1)*2+(q&1);
                size_t fi=(((size_t)ten*4+l)*64+c)*4+wg;
                bnxt[q]=(lane<32)? wwf4[fi*32+lane] : make_uint4(0,0,0,0);
            }
        }
        __syncthreads();
        // step B: per-thread (ni, mi): acc[w] += msg[ni][c][mi] * Wn[l(mi)][c][ni][w]
        #pragma unroll
        for(int cj=0;cj<2;++cj){
            int c=ch*2+cj;
            float mv=bfs(msgS[(c*16+ni)*16+mi]);
            const float* wr=&WnS[((lm*2+cj)*16+ni)*68];
            #pragma unroll
            for(int wq=0;wq<16;++wq){
                float4 qv=*(const float4*)(wr+wq*4);
                acc[wq*4+0]+=mv*qv.x; acc[wq*4+1]+=mv*qv.y;
                acc[wq*4+2]+=mv*qv.z; acc[wq*4+3]+=mv*qv.w;
            }
        }
        if(ch<31){
            #pragma unroll
            for(int q=0;q<8;++q) bcur[q]=bnxt[q];
        }
        __syncthreads();
    }
    // epilogue: write out[nb+ni][w][mi]
    float* op=base+(size_t)(nb+ni)*1024+mi;
    #pragma unroll
    for(int w=0;w<64;++w) op[(size_t)w*16]=acc[w];
}

extern "C" void kernel_launch(void* const* d_in, const int* in_sizes, int n_in,
                              void* d_out, int out_size, void* d_ws, size_t ws_size,
                              hipStream_t stream) {
    const float* node_attrs=(const float*)d_in[0];
    const float* node_feats=(const float*)d_in[1];
    const float* edge_attrs=(const float*)d_in[2];
    const float* edge_feats=(const float*)d_in[3];
    const int*   eidx_in  =(const int*)  d_in[4];
    const int*   sender   =eidx_in;
    const int*   recv     =eidx_in+N_EDGES;
    const float* mminv    =(const float*)d_in[5];
    const float* mattr    =(const float*)d_in[6];
    const float* wup      =(const float*)d_in[7];
    const float* wr0      =(const float*)d_in[8];
    const float* wr1      =(const float*)d_in[9];
    const float* wr2      =(const float*)d_in[10];
    const float* wr3      =(const float*)d_in[11];
    const float* wtr      =(const float*)d_in[12];
    const float* wdens    =(const float*)d_in[13];
    const float* wlin     =(const float*)d_in[14];
    const float* wmlin    =(const float*)d_in[15];
    const float* wskip    =(const float*)d_in[16];
    const float* wmskip   =(const float*)d_in[17];

    char* ws=(char*)d_ws;
    float*          x     =(float*)(ws+0);                      //  2 MB
    unsigned short* wxc   =(unsigned short*)(ws+2097152);       // 64 MB
    float*          man   =(float*)(ws+69206016);               //  4 MB
    float*          ed    =(float*)(ws+73400320);               // 256 KB
    unsigned short* wbig  =(unsigned short*)(ws+73662464);      // 64 KB
    unsigned*       wwf   =(unsigned*)(ws+73728000);            //  2 MB
    int*            cnt   =(int*)(ws+75825152);                 // 32 KB
    int*            rowptr=(int*)(ws+75857920);                 // 32 KB + 4
    int*            cur   =(int*)(ws+75890944);                 // 32 KB
    int*            elist =(int*)(ws+75923712);                 // 256 KB
    if(ws_size < (size_t)76185856) return;   // insufficient scratch: fail loudly

    float* out=(float*)d_out;

    hipMemsetAsync(cnt,0,32768,stream);
    k_linup  <<<dim3(2048),dim3(256),0,stream>>>(node_feats,wup,x);
    k_wbig   <<<dim3(64),  dim3(256),0,stream>>>(wr3,wtr,wbig);
    k_wwf    <<<dim3(512), dim3(256),0,stream>>>(wlin,wmlin,wskip,wmskip,wwf);
    k_count  <<<dim3(256), dim3(256),0,stream>>>(recv,cnt);
    k_scan   <<<dim3(1),   dim3(1024),0,stream>>>(cnt,rowptr,cur);
    k_scatter<<<dim3(256), dim3(256),0,stream>>>(recv,cur,elist);
    k_edge   <<<dim3(1024),dim3(256),0,stream>>>(edge_feats,mminv,mattr,sender,
                                                 wr0,wr1,wr2,wdens,wbig,x,wxc,man,ed);
    k_gather <<<dim3(2048),dim3(256),0,stream>>>(rowptr,elist,wxc,edge_attrs,man,ed,out);
    k_final2 <<<dim3(1024),dim3(256),0,stream>>>(node_attrs,wwf,out);
}

// Round 3
// 333.163 us; speedup vs baseline: 1.5639x; 1.0860x over previous
//
#include <hip/hip_runtime.h>

// Problem constants
#define N_NODES 8192
#define N_EDGES 65536

typedef __attribute__((ext_vector_type(8))) short bf16x8;
typedef __attribute__((ext_vector_type(4))) float f32x4;

// ---------- bf16 helpers (OCP bf16 = top 16 bits of f32, RNE) ----------
static __device__ __forceinline__ float bfl(unsigned v){ unsigned u=v<<16; float f; __builtin_memcpy(&f,&u,4); return f; }
static __device__ __forceinline__ float bfh(unsigned v){ unsigned u=v&0xffff0000u; float f; __builtin_memcpy(&f,&u,4); return f; }
static __device__ __forceinline__ float bfs(unsigned short h){ unsigned u=((unsigned)h)<<16; float f; __builtin_memcpy(&f,&u,4); return f; }
static __device__ __forceinline__ unsigned short f2bf(float f){ unsigned u; __builtin_memcpy(&u,&f,4); u += 0x7fffu + ((u>>16)&1u); return (unsigned short)(u>>16); }
static __device__ __forceinline__ unsigned pk(float a, float b){ return (unsigned)f2bf(a) | ((unsigned)f2bf(b)<<16); }
static __device__ __forceinline__ float silu_f(float v){ return v/(1.f+__expf(-v)); }

// ---------- K1: x = node_feats @ W_up / 8  -> ws.x [N,64] f32 ----------
__global__ __launch_bounds__(256) void k_linup(const float* __restrict__ nf,
                                               const float* __restrict__ wup,
                                               float* __restrict__ x){
    __shared__ float s[4][64];
    const int t=threadIdx.x, wv=t>>6, lane=t&63;
    const int n=blockIdx.x*4+wv;
    s[wv][lane]=nf[(size_t)n*64+lane];
    __syncthreads();
    float acc=0.f;
    for(int c=0;c<64;++c) acc += s[wv][c]*wup[c*64+lane];
    x[(size_t)n*64+lane]=acc*0.125f;
}

// ---------- prep: W_big2[i][j][s] bf16: s<4 -> W_r3[i][s*64+j]/8 ; s>=4 -> (W_r3@W_trans)[i][(s-4)*64+j]/128
__global__ __launch_bounds__(256) void k_wbig(const float* __restrict__ wr3,
                                              const float* __restrict__ wtr,
                                              unsigned short* __restrict__ wbig){
    const int i=blockIdx.x, t=threadIdx.x, j=t&63, sl=t>>6;
    wbig[((size_t)i*64+j)*8+sl]=f2bf(wr3[i*256+sl*64+j]*0.125f);
    float acc=0.f;
    for(int k=0;k<256;++k) acc += wr3[i*256+k]*wtr[k*256+sl*64+j];
    wbig[((size_t)i*64+j)*8+4+sl]=f2bf(acc*(1.f/128.f));
}

// ---------- prep: MFMA B-fragment table for the fused node contraction.
// WW[l,c,v,w] = sum_u Wlin[l,c,u]*Wskip[l,u,v,w] * (1/256 or 1/4096)
// Fragment (ten,l,c,wg): lane(0..31) holds 8 bf16 = WW[l,c, v=(lane>>4)*8+e, w=wg*16+(lane&15)]
__global__ __launch_bounds__(256) void k_wwf(const float* __restrict__ wlin,
                                             const float* __restrict__ wmlin,
                                             const float* __restrict__ wskip,
                                             const float* __restrict__ wmskip,
                                             unsigned* __restrict__ wwf){
    const int b=blockIdx.x, ten=b>>8, lc=b&255, l=lc>>6, c=lc&63;
    const float* WL = ten? wmlin:wlin;
    const float* WS = ten? wmskip:wskip;
    const float scale = ten? (1.f/4096.f):(1.f/256.f);
    const int t=threadIdx.x, wg=t>>6, s=t&63, lane=s>>1, half=s&1;
    const int kg=lane>>4, w=wg*16+(lane&15);
    const int v0=kg*8+half*4;
    float a0=0,a1=0,a2=0,a3=0;
    for(int u=0;u<64;++u){
        float wl=WL[(l*64+c)*64+u];
        const float* wsp=&WS[(((l*64+u)*16+v0)*64)+w];
        a0+=wl*wsp[0]; a1+=wl*wsp[64]; a2+=wl*wsp[128]; a3+=wl*wsp[192];
    }
    size_t fi=(((size_t)ten*4+l)*64+c)*4+wg;
    unsigned* op=wwf + (fi*32+lane)*4 + half*2;
    op[0]=pk(a0*scale,a1*scale); op[1]=pk(a2*scale,a3*scale);
}

// ---------- CSR build ----------
__global__ __launch_bounds__(256) void k_count(const int* __restrict__ recv, int* __restrict__ cnt){
    int e=blockIdx.x*256+threadIdx.x;
    atomicAdd(&cnt[recv[e]],1);
}
__global__ __launch_bounds__(1024) void k_scan(const int* __restrict__ cnt, int* __restrict__ rowptr, int* __restrict__ cur){
    __shared__ int s[1024];
    const int t=threadIdx.x;
    int c[8]; int sum=0;
    #pragma unroll
    for(int i=0;i<8;++i){ c[i]=cnt[t*8+i]; sum+=c[i]; }
    s[t]=sum; __syncthreads();
    for(int off=1;off<1024;off<<=1){
        int v=s[t]; int add=(t>=off)? s[t-off]:0;
        __syncthreads();
        s[t]=v+add;
        __syncthreads();
    }
    int run=s[t]-sum;
    #pragma unroll
    for(int i=0;i<8;++i){ rowptr[t*8+i]=run; cur[t*8+i]=run; run+=c[i]; }
    if(t==1023) rowptr[8192]=run;
}
__global__ __launch_bounds__(256) void k_scatter(const int* __restrict__ recv, int* __restrict__ cur, int* __restrict__ elist){
    int e=blockIdx.x*256+threadIdx.x;
    int r=recv[e];
    int p=atomicAdd(&cur[r],1);
    elist[p]=e;
}

// ---------- K2: per-edge radial MLP + weight apply. Writes wxc[e][c][8] bf16 (wx l0..3, wxm l0..3), man[e][16], ed[e]
__global__ __launch_bounds__(256) void k_edge(
    const float* __restrict__ ef, const float* __restrict__ mminv,
    const float* __restrict__ mattr, const int* __restrict__ sender,
    const float* __restrict__ wr0, const float* __restrict__ wr1,
    const float* __restrict__ wr2, const float* __restrict__ wdens,
    const unsigned short* __restrict__ wbig, const float* __restrict__ x,
    unsigned short* __restrict__ wxc, float* __restrict__ man, float* __restrict__ ed)
{
    __shared__ unsigned short w0s[1024];
    __shared__ unsigned short w1s[4096];
    __shared__ unsigned short w2s[4096];
    __shared__ float hA[64][64];
    __shared__ float hB[64][64];
    __shared__ int sbuf[64];
    const int t=threadIdx.x;
    const int tile=blockIdx.x*64;
    for(int q=t;q<1024;q+=256) w0s[q]=f2bf(wr0[q]*0.25f);
    for(int q=t;q<4096;q+=256){ w1s[q]=f2bf(wr1[q]*0.125f); w2s[q]=f2bf(wr2[q]*0.125f); }
    const int wv=t>>6, el=t&63, e=tile+el;
    if(wv==0){
        sbuf[el]=sender[e];
    } else if(wv==1){
        float acc=0.f;
        #pragma unroll
        for(int r=0;r<8;++r){ float v=ef[(size_t)e*8+r]; hA[el][r]=v; acc+=v*wdens[r]; }
        acc*=0.35355339059327373f;
        float q2=acc*acc;
        float ex=__expf(2.f*q2);
        ed[e]=1.f-2.f/(ex+1.f);
    } else if(wv==2){
        int s=sender[e];
        #pragma unroll
        for(int r=0;r<8;++r) hA[el][8+r]=mminv[(size_t)s*8+r];
    } else {
        int s=sender[e];
        #pragma unroll
        for(int m=0;m<16;++m) man[(size_t)e*16+m]=mattr[(size_t)s*16+m];
    }
    __syncthreads();
    const int j=el, eg=wv;
    for(int k4=0;k4<4;++k4){
        int e0=eg*16+k4*4;
        float a0=0,a1=0,a2=0,a3=0;
        for(int i=0;i<16;++i){
            float w=bfs(w0s[i*64+j]);
            a0+=hA[e0+0][i]*w; a1+=hA[e0+1][i]*w; a2+=hA[e0+2][i]*w; a3+=hA[e0+3][i]*w;
        }
        hB[e0+0][j]=silu_f(a0); hB[e0+1][j]=silu_f(a1); hB[e0+2][j]=silu_f(a2); hB[e0+3][j]=silu_f(a3);
    }
    __syncthreads();
    for(int k4=0;k4<4;++k4){
        int e0=eg*16+k4*4;
        float a0=0,a1=0,a2=0,a3=0;
        for(int i=0;i<64;++i){
            float w=bfs(w1s[i*64+j]);
            a0+=hB[e0+0][i]*w; a1+=hB[e0+1][i]*w; a2+=hB[e0+2][i]*w; a3+=hB[e0+3][i]*w;
        }
        hA[e0+0][j]=silu_f(a0); hA[e0+1][j]=silu_f(a1); hA[e0+2][j]=silu_f(a2); hA[e0+3][j]=silu_f(a3);
    }
    __syncthreads();
    for(int k4=0;k4<4;++k4){
        int e0=eg*16+k4*4;
        float a0=0,a1=0,a2=0,a3=0;
        for(int i=0;i<64;++i){
            float w=bfs(w2s[i*64+j]);
            a0+=hA[e0+0][i]*w; a1+=hA[e0+1][i]*w; a2+=hA[e0+2][i]*w; a3+=hA[e0+3][i]*w;
        }
        hB[e0+0][j]=silu_f(a0); hB[e0+1][j]=silu_f(a1); hB[e0+2][j]=silu_f(a2); hB[e0+3][j]=silu_f(a3);
    }
    __syncthreads();
    float accw[16][4]; float accm[16][4];
    #pragma unroll
    for(int eo=0;eo<16;++eo){
        #pragma unroll
        for(int l=0;l<4;++l){ accw[eo][l]=0.f; accm[eo][l]=0.f; }
    }
    const int e0=eg*16;
    for(int i=0;i<64;++i){
        uint4 r=*(const uint4*)(wbig+((size_t)i*64+j)*8);
        float w0=bfl(r.x),w1=bfh(r.x),w2=bfl(r.y),w3=bfh(r.y);
        float m0=bfl(r.z),m1=bfh(r.z),m2=bfl(r.w),m3=bfh(r.w);
        #pragma unroll
        for(int eo=0;eo<16;++eo){
            float h=hB[e0+eo][i];
            accw[eo][0]+=h*w0; accw[eo][1]+=h*w1; accw[eo][2]+=h*w2; accw[eo][3]+=h*w3;
            accm[eo][0]+=h*m0; accm[eo][1]+=h*m1; accm[eo][2]+=h*m2; accm[eo][3]+=h*m3;
        }
    }
    #pragma unroll
    for(int eo=0;eo<16;++eo){
        int elc=e0+eo;
        int s=sbuf[elc];
        float xj=x[(size_t)s*64+j];
        uint4 o;
        o.x=pk(accw[eo][0]*xj, accw[eo][1]*xj);
        o.y=pk(accw[eo][2]*xj, accw[eo][3]*xj);
        o.z=pk(accm[eo][0]*xj, accm[eo][1]*xj);
        o.w=pk(accm[eo][2]*xj, accm[eo][3]*xj);
        *(uint4*)(wxc+((size_t)(tile+elc)*64+j)*8)=o;
    }
}

// ---------- K3: wave-per-node gather; writes msgd (msg/(1+D)) and mm_raw into d_out
__global__ __launch_bounds__(256) void k_gather(
    const int* __restrict__ rowptr, const int* __restrict__ elist,
    const unsigned short* __restrict__ wxc, const float* __restrict__ ea,
    const float* __restrict__ man, const float* __restrict__ ed,
    float* __restrict__ out)
{
    const int t=threadIdx.x, wv=t>>6, lane=t&63;
    const int n=blockIdx.x*4+wv;
    const int r0=rowptr[n], r1=rowptr[n+1];
    float msg[16]; float mm[16];
    #pragma unroll
    for(int m=0;m<16;++m){ msg[m]=0.f; mm[m]=0.f; }
    float dens=0.f;
    for(int k=r0;k<r1;++k){
        int e=elist[k];
        uint4 r=*(const uint4*)(wxc+((size_t)e*64+lane)*8);
        float wx0=bfl(r.x),wx1=bfh(r.x),wx2=bfl(r.y),wx3=bfh(r.y);
        float wm0=bfl(r.z),wm1=bfh(r.z),wm2=bfl(r.w),wm3=bfh(r.w);
        dens+=ed[e];
        const float4* eap=(const float4*)(ea+(size_t)e*16);
        const float4* map=(const float4*)(man+(size_t)e*16);
        float4 A0=eap[0],A1=eap[1],A2=eap[2],A3=eap[3];
        float4 B0=map[0],B1=map[1],B2=map[2],B3=map[3];
        msg[0]+=wx0*A0.x;
        msg[1]+=wx1*A0.y;  msg[2]+=wx1*A0.z;  msg[3]+=wx1*A0.w;
        msg[4]+=wx2*A1.x;  msg[5]+=wx2*A1.y;  msg[6]+=wx2*A1.z;  msg[7]+=wx2*A1.w;  msg[8]+=wx2*A2.x;
        msg[9]+=wx3*A2.y;  msg[10]+=wx3*A2.z; msg[11]+=wx3*A2.w;
        msg[12]+=wx3*A3.x; msg[13]+=wx3*A3.y; msg[14]+=wx3*A3.z; msg[15]+=wx3*A3.w;
        mm[0]+=wm0*B0.x;
        mm[1]+=wm1*B0.y;  mm[2]+=wm1*B0.z;  mm[3]+=wm1*B0.w;
        mm[4]+=wm2*B1.x;  mm[5]+=wm2*B1.y;  mm[6]+=wm2*B1.z;  mm[7]+=wm2*B1.w;  mm[8]+=wm2*B2.x;
        mm[9]+=wm3*B2.y;  mm[10]+=wm3*B2.z; mm[11]+=wm3*B2.w;
        mm[12]+=wm3*B3.x; mm[13]+=wm3*B3.y; mm[14]+=wm3*B3.z; mm[15]+=wm3*B3.w;
    }
    float inv=1.f/(1.f+dens);
    float* mp=out+(size_t)n*1024+lane*16;
    ((float4*)mp)[0]=make_float4(msg[0]*inv,msg[1]*inv,msg[2]*inv,msg[3]*inv);
    ((float4*)mp)[1]=make_float4(msg[4]*inv,msg[5]*inv,msg[6]*inv,msg[7]*inv);
    ((float4*)mp)[2]=make_float4(msg[8]*inv,msg[9]*inv,msg[10]*inv,msg[11]*inv);
    ((float4*)mp)[3]=make_float4(msg[12]*inv,msg[13]*inv,msg[14]*inv,msg[15]*inv);
    float* qp=out+8388608+(size_t)n*1024+lane*16;
    ((float4*)qp)[0]=make_float4(mm[0],mm[1],mm[2],mm[3]);
    ((float4*)qp)[1]=make_float4(mm[4],mm[5],mm[6],mm[7]);
    ((float4*)qp)[2]=make_float4(mm[8],mm[9],mm[10],mm[11]);
    ((float4*)qp)[3]=make_float4(mm[12],mm[13],mm[14],mm[15]);
}

// ---------- K4: fused per_l_linear + skip_tp via MFMA (step A) + VALU outer-product (step B).
// Step A (MFMA): Wn[n, c, w] = sum_v attrs_bf16[n,v] * WWf[l,c,v,w]   (K=16 padded to 32)
// Step B (VALU): thread (ni,wq) owns acc[16m][4w]: acc[m][wi] += msg[ni,c,m] * Wn[l(m),c,ni,wq*4+wi]
// In-place on d_out per 16-node slab (staged to LDS bf16 first).
__global__ __launch_bounds__(256) void k_final2(const float* __restrict__ attrs,
                                                const unsigned* __restrict__ wwf,
                                                float* __restrict__ out){
    __shared__ float WnS[8*16*68];          // [q=l*2+cj][node 16][w pad 68] f32  (34816 B)
    __shared__ unsigned short msgS[16384];  // [c][node][m] bf16                  (32768 B)
    const int blk=blockIdx.x, ten=blk>>9, nb=(blk&511)*16;
    float* base=out+(size_t)ten*8388608;
    const int t=threadIdx.x, lane=t&63, wg=t>>6;

    // phase 0: stage msg slab (f32 [n][c][m]) -> msgS bf16 [c][n][m]
    const float4* src=(const float4*)(base+(size_t)nb*1024);
    #pragma unroll
    for(int j=0;j<16;++j){
        int idx=t+256*j;
        float4 f=src[idx];
        int n=idx>>8, c=(idx>>2)&63, m0=(idx&3)<<2;
        unsigned* dst=(unsigned*)&msgS[(c*16+n)*16+m0];
        dst[0]=pk(f.x,f.y); dst[1]=pk(f.z,f.w);
    }
    // A-fragment: attrs[nb+row][v], row=lane&15, v=(lane>>4)*8+e (zero for lane>=32)
    bf16x8 afrag;
    {
        int nloc=lane&15, kg=lane>>4;
        if(kg<2){
            const float* ap=attrs+(size_t)(nb+nloc)*16+kg*8;
            #pragma unroll
            for(int i=0;i<8;++i) afrag[i]=(short)f2bf(ap[i]);
        } else {
            #pragma unroll
            for(int i=0;i<8;++i) afrag[i]=0;
        }
    }
    const int ni=t>>4, wq=t&15;   // step-B thread role: node ni, w-quad wq
    float acc[64];                // acc[m*4+wi]
    #pragma unroll
    for(int i=0;i<64;++i) acc[i]=0.f;

    const uint4* wwf4=(const uint4*)wwf;
    uint4 bcur[8], bnxt[8];
    #pragma unroll
    for(int q=0;q<8;++q){              // q = l*2+cj, chunk 0 -> c=cj
        int l=q>>1, c=q&1;
        size_t fi=(((size_t)ten*4+l)*64+c)*4+wg;
        bcur[q]=(lane<32)? wwf4[fi*32+lane] : make_uint4(0,0,0,0);
    }
    __syncthreads();

    for(int ch=0;ch<32;++ch){
        // step A: 8 MFMAs (this wave's w-group), write Wn f32 to LDS (pad-68 rows)
        const int colw=wg*16+(lane&15);
        const int g4=(lane>>4)*4;
        #pragma unroll
        for(int q=0;q<8;++q){
            bf16x8 b; __builtin_memcpy(&b,&bcur[q],16);
            f32x4 z={0.f,0.f,0.f,0.f};
            f32x4 d=__builtin_amdgcn_mfma_f32_16x16x32_bf16(afrag,b,z,0,0,0);
            float* wp=&WnS[(q*16+g4)*68+colw];
            wp[0]=d[0]; wp[68]=d[1]; wp[136]=d[2]; wp[204]=d[3];
        }
        // prefetch next chunk's B-fragments (hidden under step B)
        if(ch<31){
            #pragma unroll
            for(int q=0;q<8;++q){
                int l=q>>1, c=(ch+1)*2+(q&1);
                size_t fi=(((size_t)ten*4+l)*64+c)*4+wg;
                bnxt[q]=(lane<32)? wwf4[fi*32+lane] : make_uint4(0,0,0,0);
            }
        }
        __syncthreads();
        // step B: outer-product per (ni,wq): acc[m][wi] += msg[ni][c][m] * Wn[l(m)][c][ni][wq*4+wi]
        #pragma unroll
        for(int cj=0;cj<2;++cj){
            int c=ch*2+cj;
            float4 wn[4];
            #pragma unroll
            for(int l=0;l<4;++l) wn[l]=*(const float4*)&WnS[((l*2+cj)*16+ni)*68+wq*4];
            const unsigned* mp=(const unsigned*)&msgS[(c*16+ni)*16];
            float mv[16];
            #pragma unroll
            for(int h=0;h<8;++h){ unsigned u=mp[h]; mv[2*h]=bfl(u); mv[2*h+1]=bfh(u); }
            #pragma unroll
            for(int m=0;m<16;++m){
                const int lm=(m==0)?0:(m<4)?1:(m<9)?2:3;
                acc[m*4+0]+=mv[m]*wn[lm].x;
                acc[m*4+1]+=mv[m]*wn[lm].y;
                acc[m*4+2]+=mv[m]*wn[lm].z;
                acc[m*4+3]+=mv[m]*wn[lm].w;
            }
        }
        if(ch<31){
            #pragma unroll
            for(int q=0;q<8;++q) bcur[q]=bnxt[q];
        }
        __syncthreads();
    }
    // epilogue: thread (ni,wq) writes out[nb+ni][w=wq*4+wi][m=0..15]
    #pragma unroll
    for(int wi=0;wi<4;++wi){
        float* op=base+(size_t)(nb+ni)*1024+(wq*4+wi)*16;
        ((float4*)op)[0]=make_float4(acc[0*4+wi], acc[1*4+wi], acc[2*4+wi], acc[3*4+wi]);
        ((float4*)op)[1]=make_float4(acc[4*4+wi], acc[5*4+wi], acc[6*4+wi], acc[7*4+wi]);
        ((float4*)op)[2]=make_float4(acc[8*4+wi], acc[9*4+wi], acc[10*4+wi], acc[11*4+wi]);
        ((float4*)op)[3]=make_float4(acc[12*4+wi],acc[13*4+wi],acc[14*4+wi],acc[15*4+wi]);
    }
}

extern "C" void kernel_launch(void* const* d_in, const int* in_sizes, int n_in,
                              void* d_out, int out_size, void* d_ws, size_t ws_size,
                              hipStream_t stream) {
    const float* node_attrs=(const float*)d_in[0];
    const float* node_feats=(const float*)d_in[1];
    const float* edge_attrs=(const float*)d_in[2];
    const float* edge_feats=(const float*)d_in[3];
    const int*   eidx_in  =(const int*)  d_in[4];
    const int*   sender   =eidx_in;
    const int*   recv     =eidx_in+N_EDGES;
    const float* mminv    =(const float*)d_in[5];
    const float* mattr    =(const float*)d_in[6];
    const float* wup      =(const float*)d_in[7];
    const float* wr0      =(const float*)d_in[8];
    const float* wr1      =(const float*)d_in[9];
    const float* wr2      =(const float*)d_in[10];
    const float* wr3      =(const float*)d_in[11];
    const float* wtr      =(const float*)d_in[12];
    const float* wdens    =(const float*)d_in[13];
    const float* wlin     =(const float*)d_in[14];
    const float* wmlin    =(const float*)d_in[15];
    const float* wskip    =(const float*)d_in[16];
    const float* wmskip   =(const float*)d_in[17];

    char* ws=(char*)d_ws;
    float*          x     =(float*)(ws+0);                      //  2 MB
    unsigned short* wxc   =(unsigned short*)(ws+2097152);       // 64 MB
    float*          man   =(float*)(ws+69206016);               //  4 MB
    float*          ed    =(float*)(ws+73400320);               // 256 KB
    unsigned short* wbig  =(unsigned short*)(ws+73662464);      // 64 KB
    unsigned*       wwf   =(unsigned*)(ws+73728000);            //  2 MB
    int*            cnt   =(int*)(ws+75825152);                 // 32 KB
    int*            rowptr=(int*)(ws+75857920);                 // 32 KB + 4
    int*            cur   =(int*)(ws+75890944);                 // 32 KB
    int*            elist =(int*)(ws+75923712);                 // 256 KB
    if(ws_size < (size_t)76185856) return;   // insufficient scratch: fail loudly

    float* out=(float*)d_out;

    hipMemsetAsync(cnt,0,32768,stream);
    k_linup  <<<dim3(2048),dim3(256),0,stream>>>(node_feats,wup,x);
    k_wbig   <<<dim3(64),  dim3(256),0,stream>>>(wr3,wtr,wbig);
    k_wwf    <<<dim3(512), dim3(256),0,stream>>>(wlin,wmlin,wskip,wmskip,wwf);
    k_count  <<<dim3(256), dim3(256),0,stream>>>(recv,cnt);
    k_scan   <<<dim3(1),   dim3(1024),0,stream>>>(cnt,rowptr,cur);
    k_scatter<<<dim3(256), dim3(256),0,stream>>>(recv,cur,elist);
    k_edge   <<<dim3(1024),dim3(256),0,stream>>>(edge_feats,mminv,mattr,sender,
                                                 wr0,wr1,wr2,wdens,wbig,x,wxc,man,ed);
    k_gather <<<dim3(2048),dim3(256),0,stream>>>(rowptr,elist,wxc,edge_attrs,man,ed,out);
    k_final2 <<<dim3(1024),dim3(256),0,stream>>>(node_attrs,wwf,out);
}

// Round 4
// 258.524 us; speedup vs baseline: 2.0154x; 1.2887x over previous
//
#include <hip/hip_runtime.h>

// Problem constants
#define N_NODES 8192
#define N_EDGES 65536

typedef __attribute__((ext_vector_type(8))) short bf16x8;
typedef __attribute__((ext_vector_type(4))) float f32x4;

// ---------- bf16 helpers (OCP bf16 = top 16 bits of f32, RNE) ----------
static __device__ __forceinline__ float bfl(unsigned v){ unsigned u=v<<16; float f; __builtin_memcpy(&f,&u,4); return f; }
static __device__ __forceinline__ float bfh(unsigned v){ unsigned u=v&0xffff0000u; float f; __builtin_memcpy(&f,&u,4); return f; }
static __device__ __forceinline__ float bfs(unsigned short h){ unsigned u=((unsigned)h)<<16; float f; __builtin_memcpy(&f,&u,4); return f; }
static __device__ __forceinline__ unsigned short f2bf(float f){ unsigned u; __builtin_memcpy(&u,&f,4); u += 0x7fffu + ((u>>16)&1u); return (unsigned short)(u>>16); }
static __device__ __forceinline__ unsigned pk(float a, float b){ return (unsigned)f2bf(a) | ((unsigned)f2bf(b)<<16); }
static __device__ __forceinline__ float silu_f(float v){ return v/(1.f+__expf(-v)); }

// ---------- K1: x = node_feats @ W_up / 8  -> ws.x [N,64] f32 ----------
__global__ __launch_bounds__(256) void k_linup(const float* __restrict__ nf,
                                               const float* __restrict__ wup,
                                               float* __restrict__ x){
    __shared__ float s[4][64];
    const int t=threadIdx.x, wv=t>>6, lane=t&63;
    const int n=blockIdx.x*4+wv;
    s[wv][lane]=nf[(size_t)n*64+lane];
    __syncthreads();
    float acc=0.f;
    for(int c=0;c<64;++c) acc += s[wv][c]*wup[c*64+lane];
    x[(size_t)n*64+lane]=acc*0.125f;
}

// ---------- prep: MLP weight B-fragment tables (bf16, scales folded).
// Fragment layout (16x16x32): lane l holds B[k=(l>>4)*8+i][n=(l&15)] for i=0..7.
// w0f[nt][lane][i]: k<16 -> wr0[k*64+n]/4 else 0.  w1f/w2f[(nt*2+ks)][lane][i] = wr{1,2}[(ks*32+k')*64+n]/8
__global__ __launch_bounds__(256) void k_wmlp(const float* __restrict__ wr0,
                                              const float* __restrict__ wr1,
                                              const float* __restrict__ wr2,
                                              unsigned short* __restrict__ w0f,
                                              unsigned short* __restrict__ w1f,
                                              unsigned short* __restrict__ w2f){
    const int b=blockIdx.x, t=threadIdx.x;
    #pragma unroll
    for(int z=0;z<2;++z){
        int idx=t*2+z;            // 0..511
        int lane=idx>>3, i=idx&7;
        if(b<4){
            int nt=b, k=(lane>>4)*8+i, n=nt*16+(lane&15);
            float v=(k<16)? wr0[k*64+n]*0.25f : 0.f;
            w0f[(nt*64+lane)*8+i]=f2bf(v);
        } else if(b<12){
            int q=b-4, nt=q>>1, ks=q&1;
            int k=ks*32+(lane>>4)*8+i, n=nt*16+(lane&15);
            w1f[((nt*2+ks)*64+lane)*8+i]=f2bf(wr1[k*64+n]*0.125f);
        } else {
            int q=b-12, nt=q>>1, ks=q&1;
            int k=ks*32+(lane>>4)*8+i, n=nt*16+(lane&15);
            w2f[((nt*2+ks)*64+lane)*8+i]=f2bf(wr2[k*64+n]*0.125f);
        }
    }
}

// ---------- prep: phase-B A-fragment table Wtf (bf16). A = W^T, M-rows n = j*8+s (512), K = 64.
// A-frag: lane l holds A[n=mt*16+(l&15)][k=ks*32+(l>>4)*8+i].
// s<4: W[k][n] = wr3[k*256+s*64+j]/8 ; s>=4: (wr3@wtr)[k][(s-4)*64+j]/128
__global__ __launch_bounds__(256) void k_wtf(const float* __restrict__ wr3,
                                             const float* __restrict__ wtr,
                                             unsigned short* __restrict__ wtf){
    const int b=blockIdx.x;       // 0..63 = mt*2+ks
    const int mt=b>>1, ks=b&1, t=threadIdx.x;
    #pragma unroll
    for(int z=0;z<2;++z){
        int idx=t*2+z;            // 0..511
        int lane=idx>>3, i=idx&7;
        int k=ks*32+(lane>>4)*8+i;
        int n=mt*16+(lane&15);
        int j=n>>3, s=n&7;
        float v;
        if(s<4) v=wr3[k*256+s*64+j]*0.125f;
        else {
            float acc=0.f;
            for(int kk=0;kk<256;++kk) acc+=wr3[k*256+kk]*wtr[kk*256+(s-4)*64+j];
            v=acc*(1.f/128.f);
        }
        wtf[((size_t)b*64+lane)*8+i]=f2bf(v);
    }
}

// ---------- prep: MFMA B-fragment table for the fused node contraction (k_final2).
__global__ __launch_bounds__(256) void k_wwf(const float* __restrict__ wlin,
                                             const float* __restrict__ wmlin,
                                             const float* __restrict__ wskip,
                                             const float* __restrict__ wmskip,
                                             unsigned* __restrict__ wwf){
    const int b=blockIdx.x, ten=b>>8, lc=b&255, l=lc>>6, c=lc&63;
    const float* WL = ten? wmlin:wlin;
    const float* WS = ten? wmskip:wskip;
    const float scale = ten? (1.f/4096.f):(1.f/256.f);
    const int t=threadIdx.x, wg=t>>6, s=t&63, lane=s>>1, half=s&1;
    const int kg=lane>>4, w=wg*16+(lane&15);
    const int v0=kg*8+half*4;
    float a0=0,a1=0,a2=0,a3=0;
    for(int u=0;u<64;++u){
        float wl=WL[(l*64+c)*64+u];
        const float* wsp=&WS[(((l*64+u)*16+v0)*64)+w];
        a0+=wl*wsp[0]; a1+=wl*wsp[64]; a2+=wl*wsp[128]; a3+=wl*wsp[192];
    }
    size_t fi=(((size_t)ten*4+l)*64+c)*4+wg;
    unsigned* op=wwf + (fi*32+lane)*4 + half*2;
    op[0]=pk(a0*scale,a1*scale); op[1]=pk(a2*scale,a3*scale);
}

// ---------- CSR build ----------
__global__ __launch_bounds__(256) void k_count(const int* __restrict__ recv, int* __restrict__ cnt){
    int e=blockIdx.x*256+threadIdx.x;
    atomicAdd(&cnt[recv[e]],1);
}
__global__ __launch_bounds__(1024) void k_scan(const int* __restrict__ cnt, int* __restrict__ rowptr, int* __restrict__ cur){
    __shared__ int s[1024];
    const int t=threadIdx.x;
    int c[8]; int sum=0;
    #pragma unroll
    for(int i=0;i<8;++i){ c[i]=cnt[t*8+i]; sum+=c[i]; }
    s[t]=sum; __syncthreads();
    for(int off=1;off<1024;off<<=1){
        int v=s[t]; int add=(t>=off)? s[t-off]:0;
        __syncthreads();
        s[t]=v+add;
        __syncthreads();
    }
    int run=s[t]-sum;
    #pragma unroll
    for(int i=0;i<8;++i){ rowptr[t*8+i]=run; cur[t*8+i]=run; run+=c[i]; }
    if(t==1023) rowptr[8192]=run;
}
__global__ __launch_bounds__(256) void k_scatter(const int* __restrict__ recv, int* __restrict__ cur, int* __restrict__ elist){
    int e=blockIdx.x*256+threadIdx.x;
    int r=recv[e];
    int p=atomicAdd(&cur[r],1);
    elist[p]=e;
}

// ---------- K2: per-edge radial MLP + weight apply, full MFMA.
// Per block: 64 edges. h roundtrips LDS bf16 [e][k] with XOR swizzle idx = e*64 + (k ^ ((e&7)<<3)).
// L1: h1=silu(h0@W0) K=32(pad);  L2/L3: K=64.  Phase B (transposed): C[n=j*8+s][e] = sum_k Wt[n][k] h3[e][k],
// scaled by xj=x[sender[e]][j], packed bf16, stored as uint2 into wxc[e][j][8].
__global__ __launch_bounds__(256) void k_edge2(
    const float* __restrict__ ef, const float* __restrict__ mminv,
    const float* __restrict__ mattr, const int* __restrict__ sender,
    const float* __restrict__ wdens,
    const uint4* __restrict__ w0f, const uint4* __restrict__ w1f,
    const uint4* __restrict__ w2f, const uint4* __restrict__ wtf,
    const float* __restrict__ x,
    unsigned short* __restrict__ wxc, float* __restrict__ man, float* __restrict__ ed)
{
    __shared__ unsigned short hA[4096];   // 8KB  [e][k] bf16 swizzled
    __shared__ unsigned short hB[4096];   // 8KB
    __shared__ float xs[64*68];           // 17KB [e][j pad 68]
    const int t=threadIdx.x, lane=t&63, wv=t>>6;
    const int tile=blockIdx.x*64;

    // ---- stage: x gather, man copy, h0 build, edge density ----
    {
        const int e=t>>2, q=t&3, ge=tile+e;
        const int s=sender[ge];
        const float4* xp=(const float4*)(x+(size_t)s*64+q*16);
        float4* xw=(float4*)&xs[e*68+q*16];
        xw[0]=xp[0]; xw[1]=xp[1]; xw[2]=xp[2]; xw[3]=xp[3];
        *(float4*)(man+(size_t)ge*16+q*4) = *(const float4*)(mattr+(size_t)s*16+q*4);
        const int se3=(e&7)<<3;
        if(q==0){
            float4 f0=*(const float4*)(ef+(size_t)ge*8);
            float4 f1=*(const float4*)(ef+(size_t)ge*8+4);
            uint4 o; o.x=pk(f0.x,f0.y); o.y=pk(f0.z,f0.w); o.z=pk(f1.x,f1.y); o.w=pk(f1.z,f1.w);
            *(uint4*)&hA[e*64 + (0^se3)]=o;
            float acc=f0.x*wdens[0]+f0.y*wdens[1]+f0.z*wdens[2]+f0.w*wdens[3]
                     +f1.x*wdens[4]+f1.y*wdens[5]+f1.z*wdens[6]+f1.w*wdens[7];
            acc*=0.35355339059327373f;           // 1/sqrt(8)
            float q2=acc*acc;
            float ex=__expf(2.f*q2);
            ed[ge]=1.f-2.f/(ex+1.f);             // tanh(q2)
        } else if(q==1){
            float4 f0=*(const float4*)(mminv+(size_t)s*8);
            float4 f1=*(const float4*)(mminv+(size_t)s*8+4);
            uint4 o; o.x=pk(f0.x,f0.y); o.y=pk(f0.z,f0.w); o.z=pk(f1.x,f1.y); o.w=pk(f1.z,f1.w);
            *(uint4*)&hA[e*64 + (8^se3)]=o;
        } else if(q==2){
            *(uint4*)&hA[e*64 + (16^se3)]=make_uint4(0,0,0,0);
        } else {
            *(uint4*)&hA[e*64 + (24^se3)]=make_uint4(0,0,0,0);
        }
    }
    __syncthreads();

    const int arow=wv*16+(lane&15);      // A-frag row (edge) for MLP layers
    const int akg=lane>>4;               // k-group
    const int aswz=(arow&7)<<3;
    const int dcol=lane&15;
    const int drow0=wv*16+(lane>>4)*4;

    // ---- L1: hA (h0) -> hB ----
    {
        uint4 av=*(const uint4*)&hA[arow*64+((akg*8)^aswz)];
        bf16x8 a; __builtin_memcpy(&a,&av,16);
        f32x4 d[4];
        #pragma unroll
        for(int nt=0;nt<4;++nt){
            uint4 bw=w0f[nt*64+lane];
            bf16x8 b; __builtin_memcpy(&b,&bw,16);
            f32x4 z={0.f,0.f,0.f,0.f};
            d[nt]=__builtin_amdgcn_mfma_f32_16x16x32_bf16(a,b,z,0,0,0);
        }
        #pragma unroll
        for(int nt=0;nt<4;++nt){
            #pragma unroll
            for(int r=0;r<4;++r){
                int e2=drow0+r, n=nt*16+dcol;
                hB[e2*64 + (n^((e2&7)<<3))]=f2bf(silu_f(d[nt][r]));
            }
        }
    }
    __syncthreads();

    // ---- L2: hB (h1) -> hA ----
    {
        uint4 av0=*(const uint4*)&hB[arow*64+(((0+akg)*8)^aswz)];
        uint4 av1=*(const uint4*)&hB[arow*64+(((4+akg)*8)^aswz)];
        bf16x8 a0,a1; __builtin_memcpy(&a0,&av0,16); __builtin_memcpy(&a1,&av1,16);
        f32x4 d[4];
        #pragma unroll
        for(int nt=0;nt<4;++nt){
            uint4 bw0=w1f[(nt*2+0)*64+lane];
            uint4 bw1=w1f[(nt*2+1)*64+lane];
            bf16x8 b0,b1; __builtin_memcpy(&b0,&bw0,16); __builtin_memcpy(&b1,&bw1,16);
            f32x4 z={0.f,0.f,0.f,0.f};
            d[nt]=__builtin_amdgcn_mfma_f32_16x16x32_bf16(a0,b0,z,0,0,0);
            d[nt]=__builtin_amdgcn_mfma_f32_16x16x32_bf16(a1,b1,d[nt],0,0,0);
        }
        #pragma unroll
        for(int nt=0;nt<4;++nt){
            #pragma unroll
            for(int r=0;r<4;++r){
                int e2=drow0+r, n=nt*16+dcol;
                hA[e2*64 + (n^((e2&7)<<3))]=f2bf(silu_f(d[nt][r]));
            }
        }
    }
    __syncthreads();

    // ---- L3: hA (h2) -> hB ----
    {
        uint4 av0=*(const uint4*)&hA[arow*64+(((0+akg)*8)^aswz)];
        uint4 av1=*(const uint4*)&hA[arow*64+(((4+akg)*8)^aswz)];
        bf16x8 a0,a1; __builtin_memcpy(&a0,&av0,16); __builtin_memcpy(&a1,&av1,16);
        f32x4 d[4];
        #pragma unroll
        for(int nt=0;nt<4;++nt){
            uint4 bw0=w2f[(nt*2+0)*64+lane];
            uint4 bw1=w2f[(nt*2+1)*64+lane];
            bf16x8 b0,b1; __builtin_memcpy(&b0,&bw0,16); __builtin_memcpy(&b1,&bw1,16);
            f32x4 z={0.f,0.f,0.f,0.f};
            d[nt]=__builtin_amdgcn_mfma_f32_16x16x32_bf16(a0,b0,z,0,0,0);
            d[nt]=__builtin_amdgcn_mfma_f32_16x16x32_bf16(a1,b1,d[nt],0,0,0);
        }
        #pragma unroll
        for(int nt=0;nt<4;++nt){
            #pragma unroll
            for(int r=0;r<4;++r){
                int e2=drow0+r, n=nt*16+dcol;
                hB[e2*64 + (n^((e2&7)<<3))]=f2bf(silu_f(d[nt][r]));
            }
        }
    }
    __syncthreads();

    // ---- phase B (transposed GEMM): per wave 8 M-tiles (n-range wv*128..) x 4 e-tiles x K=64 ----
    {
        bf16x8 hb[4][2];
        #pragma unroll
        for(int nt2=0;nt2<4;++nt2){
            int erow=nt2*16+(lane&15);
            int esz=(erow&7)<<3;
            #pragma unroll
            for(int ks=0;ks<2;++ks){
                uint4 v=*(const uint4*)&hB[erow*64+(((ks*4+akg)*8)^esz)];
                __builtin_memcpy(&hb[nt2][ks],&v,16);
            }
        }
        const int g=lane>>4;
        const int jo=g>>1, sh=g&1;     // j offset within M-tile; s-half (0:w, 1:m)
        for(int mt=0;mt<8;++mt){
            int mtg=wv*8+mt;
            uint4 aw0=wtf[(mtg*2+0)*64+lane];
            uint4 aw1=wtf[(mtg*2+1)*64+lane];
            bf16x8 a0,a1; __builtin_memcpy(&a0,&aw0,16); __builtin_memcpy(&a1,&aw1,16);
            int j=mtg*2+jo;
            #pragma unroll
            for(int nt2=0;nt2<4;++nt2){
                f32x4 z={0.f,0.f,0.f,0.f};
                f32x4 d=__builtin_amdgcn_mfma_f32_16x16x32_bf16(a0,hb[nt2][0],z,0,0,0);
                d=__builtin_amdgcn_mfma_f32_16x16x32_bf16(a1,hb[nt2][1],d,0,0,0);
                int eloc=nt2*16+(lane&15);
                float xj=xs[eloc*68+j];
                uint2 o; o.x=pk(d[0]*xj,d[1]*xj); o.y=pk(d[2]*xj,d[3]*xj);
                *(uint2*)&wxc[((size_t)(tile+eloc)*64+j)*8+sh*4]=o;
            }
        }
    }
}

// ---------- K3: wave-per-node gather; writes msgd (msg/(1+D)) and mm_raw into d_out
__global__ __launch_bounds__(256) void k_gather(
    const int* __restrict__ rowptr, const int* __restrict__ elist,
    const unsigned short* __restrict__ wxc, const float* __restrict__ ea,
    const float* __restrict__ man, const float* __restrict__ ed,
    float* __restrict__ out)
{
    const int t=threadIdx.x, wv=t>>6, lane=t&63;
    const int n=blockIdx.x*4+wv;
    const int r0=rowptr[n], r1=rowptr[n+1];
    float msg[16]; float mm[16];
    #pragma unroll
    for(int m=0;m<16;++m){ msg[m]=0.f; mm[m]=0.f; }
    float dens=0.f;
    for(int k=r0;k<r1;++k){
        int e=elist[k];
        uint4 r=*(const uint4*)(wxc+((size_t)e*64+lane)*8);
        float wx0=bfl(r.x),wx1=bfh(r.x),wx2=bfl(r.y),wx3=bfh(r.y);
        float wm0=bfl(r.z),wm1=bfh(r.z),wm2=bfl(r.w),wm3=bfh(r.w);
        dens+=ed[e];
        const float4* eap=(const float4*)(ea+(size_t)e*16);
        const float4* map=(const float4*)(man+(size_t)e*16);
        float4 A0=eap[0],A1=eap[1],A2=eap[2],A3=eap[3];
        float4 B0=map[0],B1=map[1],B2=map[2],B3=map[3];
        msg[0]+=wx0*A0.x;
        msg[1]+=wx1*A0.y;  msg[2]+=wx1*A0.z;  msg[3]+=wx1*A0.w;
        msg[4]+=wx2*A1.x;  msg[5]+=wx2*A1.y;  msg[6]+=wx2*A1.z;  msg[7]+=wx2*A1.w;  msg[8]+=wx2*A2.x;
        msg[9]+=wx3*A2.y;  msg[10]+=wx3*A2.z; msg[11]+=wx3*A2.w;
        msg[12]+=wx3*A3.x; msg[13]+=wx3*A3.y; msg[14]+=wx3*A3.z; msg[15]+=wx3*A3.w;
        mm[0]+=wm0*B0.x;
        mm[1]+=wm1*B0.y;  mm[2]+=wm1*B0.z;  mm[3]+=wm1*B0.w;
        mm[4]+=wm2*B1.x;  mm[5]+=wm2*B1.y;  mm[6]+=wm2*B1.z;  mm[7]+=wm2*B1.w;  mm[8]+=wm2*B2.x;
        mm[9]+=wm3*B2.y;  mm[10]+=wm3*B2.z; mm[11]+=wm3*B2.w;
        mm[12]+=wm3*B3.x; mm[13]+=wm3*B3.y; mm[14]+=wm3*B3.z; mm[15]+=wm3*B3.w;
    }
    float inv=1.f/(1.f+dens);
    float* mp=out+(size_t)n*1024+lane*16;
    ((float4*)mp)[0]=make_float4(msg[0]*inv,msg[1]*inv,msg[2]*inv,msg[3]*inv);
    ((float4*)mp)[1]=make_float4(msg[4]*inv,msg[5]*inv,msg[6]*inv,msg[7]*inv);
    ((float4*)mp)[2]=make_float4(msg[8]*inv,msg[9]*inv,msg[10]*inv,msg[11]*inv);
    ((float4*)mp)[3]=make_float4(msg[12]*inv,msg[13]*inv,msg[14]*inv,msg[15]*inv);
    float* qp=out+8388608+(size_t)n*1024+lane*16;
    ((float4*)qp)[0]=make_float4(mm[0],mm[1],mm[2],mm[3]);
    ((float4*)qp)[1]=make_float4(mm[4],mm[5],mm[6],mm[7]);
    ((float4*)qp)[2]=make_float4(mm[8],mm[9],mm[10],mm[11]);
    ((float4*)qp)[3]=make_float4(mm[12],mm[13],mm[14],mm[15]);
}

// ---------- K4: fused per_l_linear + skip_tp via MFMA (step A) + VALU outer-product (step B).
__global__ __launch_bounds__(256) void k_final2(const float* __restrict__ attrs,
                                                const unsigned* __restrict__ wwf,
                                                float* __restrict__ out){
    __shared__ float WnS[8*16*68];          // [q=l*2+cj][node 16][w pad 68] f32  (34816 B)
    __shared__ unsigned short msgS[16384];  // [c][node][m] bf16                  (32768 B)
    const int blk=blockIdx.x, ten=blk>>9, nb=(blk&511)*16;
    float* base=out+(size_t)ten*8388608;
    const int t=threadIdx.x, lane=t&63, wg=t>>6;

    const float4* src=(const float4*)(base+(size_t)nb*1024);
    #pragma unroll
    for(int j=0;j<16;++j){
        int idx=t+256*j;
        float4 f=src[idx];
        int n=idx>>8, c=(idx>>2)&63, m0=(idx&3)<<2;
        unsigned* dst=(unsigned*)&msgS[(c*16+n)*16+m0];
        dst[0]=pk(f.x,f.y); dst[1]=pk(f.z,f.w);
    }
    bf16x8 afrag;
    {
        int nloc=lane&15, kg=lane>>4;
        if(kg<2){
            const float* ap=attrs+(size_t)(nb+nloc)*16+kg*8;
            #pragma unroll
            for(int i=0;i<8;++i) afrag[i]=(short)f2bf(ap[i]);
        } else {
            #pragma unroll
            for(int i=0;i<8;++i) afrag[i]=0;
        }
    }
    const int ni=t>>4, wq=t&15;
    float acc[64];
    #pragma unroll
    for(int i=0;i<64;++i) acc[i]=0.f;

    const uint4* wwf4=(const uint4*)wwf;
    uint4 bcur[8], bnxt[8];
    #pragma unroll
    for(int q=0;q<8;++q){
        int l=q>>1, c=q&1;
        size_t fi=(((size_t)ten*4+l)*64+c)*4+wg;
        bcur[q]=(lane<32)? wwf4[fi*32+lane] : make_uint4(0,0,0,0);
    }
    __syncthreads();

    for(int ch=0;ch<32;++ch){
        const int colw=wg*16+(lane&15);
        const int g4=(lane>>4)*4;
        #pragma unroll
        for(int q=0;q<8;++q){
            bf16x8 b; __builtin_memcpy(&b,&bcur[q],16);
            f32x4 z={0.f,0.f,0.f,0.f};
            f32x4 d=__builtin_amdgcn_mfma_f32_16x16x32_bf16(afrag,b,z,0,0,0);
            float* wp=&WnS[(q*16+g4)*68+colw];
            wp[0]=d[0]; wp[68]=d[1]; wp[136]=d[2]; wp[204]=d[3];
        }
        if(ch<31){
            #pragma unroll
            for(int q=0;q<8;++q){
                int l=q>>1, c=(ch+1)*2+(q&1);
                size_t fi=(((size_t)ten*4+l)*64+c)*4+wg;
                bnxt[q]=(lane<32)? wwf4[fi*32+lane] : make_uint4(0,0,0,0);
            }
        }
        __syncthreads();
        #pragma unroll
        for(int cj=0;cj<2;++cj){
            int c=ch*2+cj;
            float4 wn[4];
            #pragma unroll
            for(int l=0;l<4;++l) wn[l]=*(const float4*)&WnS[((l*2+cj)*16+ni)*68+wq*4];
            const unsigned* mp=(const unsigned*)&msgS[(c*16+ni)*16];
            float mv[16];
            #pragma unroll
            for(int h=0;h<8;++h){ unsigned u=mp[h]; mv[2*h]=bfl(u); mv[2*h+1]=bfh(u); }
            #pragma unroll
            for(int m=0;m<16;++m){
                const int lm=(m==0)?0:(m<4)?1:(m<9)?2:3;
                acc[m*4+0]+=mv[m]*wn[lm].x;
                acc[m*4+1]+=mv[m]*wn[lm].y;
                acc[m*4+2]+=mv[m]*wn[lm].z;
                acc[m*4+3]+=mv[m]*wn[lm].w;
            }
        }
        if(ch<31){
            #pragma unroll
            for(int q=0;q<8;++q) bcur[q]=bnxt[q];
        }
        __syncthreads();
    }
    #pragma unroll
    for(int wi=0;wi<4;++wi){
        float* op=base+(size_t)(nb+ni)*1024+(wq*4+wi)*16;
        ((float4*)op)[0]=make_float4(acc[0*4+wi], acc[1*4+wi], acc[2*4+wi], acc[3*4+wi]);
        ((float4*)op)[1]=make_float4(acc[4*4+wi], acc[5*4+wi], acc[6*4+wi], acc[7*4+wi]);
        ((float4*)op)[2]=make_float4(acc[8*4+wi], acc[9*4+wi], acc[10*4+wi], acc[11*4+wi]);
        ((float4*)op)[3]=make_float4(acc[12*4+wi],acc[13*4+wi],acc[14*4+wi],acc[15*4+wi]);
    }
}

extern "C" void kernel_launch(void* const* d_in, const int* in_sizes, int n_in,
                              void* d_out, int out_size, void* d_ws, size_t ws_size,
                              hipStream_t stream) {
    const float* node_attrs=(const float*)d_in[0];
    const float* node_feats=(const float*)d_in[1];
    const float* edge_attrs=(const float*)d_in[2];
    const float* edge_feats=(const float*)d_in[3];
    const int*   eidx_in  =(const int*)  d_in[4];
    const int*   sender   =eidx_in;
    const int*   recv     =eidx_in+N_EDGES;
    const float* mminv    =(const float*)d_in[5];
    const float* mattr    =(const float*)d_in[6];
    const float* wup      =(const float*)d_in[7];
    const float* wr0      =(const float*)d_in[8];
    const float* wr1      =(const float*)d_in[9];
    const float* wr2      =(const float*)d_in[10];
    const float* wr3      =(const float*)d_in[11];
    const float* wtr      =(const float*)d_in[12];
    const float* wdens    =(const float*)d_in[13];
    const float* wlin     =(const float*)d_in[14];
    const float* wmlin    =(const float*)d_in[15];
    const float* wskip    =(const float*)d_in[16];
    const float* wmskip   =(const float*)d_in[17];

    char* ws=(char*)d_ws;
    float*          x     =(float*)(ws+0);                      //  2 MB
    unsigned short* wxc   =(unsigned short*)(ws+2097152);       // 64 MB
    float*          man   =(float*)(ws+69206016);               //  4 MB
    float*          ed    =(float*)(ws+73400320);               // 256 KB
    unsigned short* wtf   =(unsigned short*)(ws+73662464);      // 64 KB
    unsigned*       wwf   =(unsigned*)(ws+73728000);            //  2 MB
    unsigned short* w0f   =(unsigned short*)(ws+75825152);      //  4 KB
    unsigned short* w1f   =(unsigned short*)(ws+75829248);      //  8 KB
    unsigned short* w2f   =(unsigned short*)(ws+75837440);      //  8 KB
    int*            cnt   =(int*)(ws+75845632);                 // 32 KB
    int*            rowptr=(int*)(ws+75878400);                 // 32 KB + 4 (pad to 75911296)
    int*            cur   =(int*)(ws+75911296);                 // 32 KB
    int*            elist =(int*)(ws+75944064);                 // 256 KB -> 76206208
    if(ws_size < (size_t)76206208) return;   // insufficient scratch: fail loudly

    float* out=(float*)d_out;

    hipMemsetAsync(cnt,0,32768,stream);
    k_linup  <<<dim3(2048),dim3(256),0,stream>>>(node_feats,wup,x);
    k_wmlp   <<<dim3(20),  dim3(256),0,stream>>>(wr0,wr1,wr2,w0f,w1f,w2f);
    k_wtf    <<<dim3(64),  dim3(256),0,stream>>>(wr3,wtr,wtf);
    k_wwf    <<<dim3(512), dim3(256),0,stream>>>(wlin,wmlin,wskip,wmskip,wwf);
    k_count  <<<dim3(256), dim3(256),0,stream>>>(recv,cnt);
    k_scan   <<<dim3(1),   dim3(1024),0,stream>>>(cnt,rowptr,cur);
    k_scatter<<<dim3(256), dim3(256),0,stream>>>(recv,cur,elist);
    k_edge2  <<<dim3(1024),dim3(256),0,stream>>>(edge_feats,mminv,mattr,sender,wdens,
                                                 (const uint4*)w0f,(const uint4*)w1f,
                                                 (const uint4*)w2f,(const uint4*)wtf,
                                                 x,wxc,man,ed);
    k_gather <<<dim3(2048),dim3(256),0,stream>>>(rowptr,elist,wxc,edge_attrs,man,ed,out);
    k_final2 <<<dim3(1024),dim3(256),0,stream>>>(node_attrs,wwf,out);
}